// Round 1
// baseline (4734.318 us; speedup 1.0000x reference)
//
#include <hip/hip_runtime.h>
#include <hip/hip_bf16.h>

typedef __hip_bfloat16 bf16;

// ---------------- constants ----------------
constexpr int B = 32, C = 64, Hh = 64, Ww = 64, HW = 4096, OC = 128;
constexpr int OCPB = 8;   // out-channels per wave

// ---------------- helpers ----------------
__device__ __forceinline__ float to_f(float x)  { return x; }
__device__ __forceinline__ float to_f(bf16 x)   { return __bfloat162float(x); }
__device__ __forceinline__ void store_o(float* p, float v) { *p = v; }
__device__ __forceinline__ void store_o(bf16* p, float v)  { *p = __float2bfloat16(v); }

// ---------------- attention softmax ----------------
// logits[b,p] = <out1[b,:,p], lin_w[p,:]> + lin_b[p]; softmax over p (4096) per batch.
__global__ __launch_bounds__(256) void attn_k(const float* __restrict__ out1,
                                              const float* __restrict__ lin_w,
                                              const float* __restrict__ lin_b,
                                              float* __restrict__ attn)
{
    int b = blockIdx.x;
    int tid = threadIdx.x;
    const float* xb = out1 + (size_t)b * C * HW;
    float lg[16];
#pragma unroll
    for (int k = 0; k < 16; ++k) {
        int p = tid + (k << 8);
        float acc = lin_b[p];
        const float* wp = lin_w + (size_t)p * C;
        for (int c = 0; c < C; ++c)
            acc = fmaf(xb[(size_t)c * HW + p], wp[c], acc);
        lg[k] = acc;
    }
    __shared__ float red[256];
    float m = -INFINITY;
#pragma unroll
    for (int k = 0; k < 16; ++k) m = fmaxf(m, lg[k]);
    red[tid] = m; __syncthreads();
    for (int s = 128; s > 0; s >>= 1) {
        if (tid < s) red[tid] = fmaxf(red[tid], red[tid + s]);
        __syncthreads();
    }
    m = red[0]; __syncthreads();
    float se = 0.f;
#pragma unroll
    for (int k = 0; k < 16; ++k) { lg[k] = __expf(lg[k] - m); se += lg[k]; }
    red[tid] = se; __syncthreads();
    for (int s = 128; s > 0; s >>= 1) {
        if (tid < s) red[tid] += red[tid + s];
        __syncthreads();
    }
    float inv = 1.0f / red[0];
#pragma unroll
    for (int k = 0; k < 16; ++k)
        attn[(size_t)b * HW + tid + (k << 8)] = lg[k] * inv;
}

// ---------------- direct 3x3 conv (pad=1), leaky-relu, OCPB oc per wave ----------------
template<typename Tin, int IC_PART, int IC_TOT>
__device__ __forceinline__ void conv_part(const Tin* __restrict__ src_b, int ic_off,
                                          const float* __restrict__ w,
                                          int oc0, int yi, int xi, float* acc)
{
    for (int ic = 0; ic < IC_PART; ++ic) {
        const Tin* src = src_b + (size_t)ic * HW;
        float v[9];
#pragma unroll
        for (int ky = 0; ky < 3; ++ky) {
            int iy = yi + ky;
            bool yok = (unsigned)iy < (unsigned)Hh;
#pragma unroll
            for (int kx = 0; kx < 3; ++kx) {
                int ix = xi + kx;
                v[ky * 3 + kx] = (yok && (unsigned)ix < (unsigned)Ww)
                                 ? to_f(src[iy * Ww + ix]) : 0.0f;
            }
        }
        const float* wp = w + ((size_t)oc0 * IC_TOT + (ic_off + ic)) * 9;
#pragma unroll
        for (int j = 0; j < OCPB; ++j) {
            const float* wj = wp + (size_t)j * IC_TOT * 9;
            float a = acc[j];
#pragma unroll
            for (int k = 0; k < 9; ++k) a = fmaf(v[k], wj[k], a);
            acc[j] = a;
        }
    }
}

template<typename Tin, typename Tout, int ICA, int ICB, int STRIDE>
__global__ __launch_bounds__(64)
void conv3x3_k(const Tin* __restrict__ inA, const Tin* __restrict__ inB,
               const float* __restrict__ w, const float* __restrict__ bias,
               Tout* __restrict__ out)
{
    constexpr int WO = Ww / STRIDE;
    int tid = threadIdx.x;
    int pix = blockIdx.x * 64 + tid;
    int yo = pix / WO, xo = pix % WO;          // WO is power of 2 -> shifts
    int oc0 = blockIdx.y * OCPB;
    int b = blockIdx.z;
    int yi = yo * STRIDE - 1, xi = xo * STRIDE - 1;
    float acc[OCPB];
#pragma unroll
    for (int j = 0; j < OCPB; ++j) acc[j] = bias[oc0 + j];
    conv_part<Tin, ICA, ICA + ICB>(inA + (size_t)b * ICA * HW, 0, w, oc0, yi, xi, acc);
    if constexpr (ICB > 0)
        conv_part<Tin, ICB, ICA + ICB>(inB + (size_t)b * ICB * HW, ICA, w, oc0, yi, xi, acc);
#pragma unroll
    for (int j = 0; j < OCPB; ++j) {
        float a = acc[j];
        a = (a >= 0.0f) ? a : 0.1f * a;
        store_o(out + ((size_t)(b * OC + oc0 + j)) * (WO * WO) + pix, a);
    }
}

// ---------------- RoI align (full-image ROI, ph=pw=32, sr=2, spatial 64x64) ----------------
template<typename F>
__device__ __forceinline__ float roi_bin(F&& fetch, int i, int j)
{
    float s = 0.f;
#pragma unroll
    for (int a = 0; a < 2; ++a) {
        float ys = (i + 0.25f + 0.5f * a) * 1.96875f;     // (64-1)/32
        int y0 = (int)floorf(ys);
        int y1 = min(y0 + 1, Hh - 1);
        float ly = ys - (float)y0, hy = 1.f - ly;
#pragma unroll
        for (int cixx = 0; cixx < 2; ++cixx) {
            float xs = (j + 0.25f + 0.5f * cixx) * 1.96875f;
            int x0 = (int)floorf(xs);
            int x1 = min(x0 + 1, Ww - 1);
            float lx = xs - (float)x0, hx = 1.f - lx;
            s += hy * hx * fetch(y0, x0) + hy * lx * fetch(y0, x1)
               + ly * hx * fetch(y1, x0) + ly * lx * fetch(y1, x1);
        }
    }
    return s * 0.25f;
}

// block_out3 = roi_align(prev * attn)
__global__ __launch_bounds__(256) void bo3_k(const bf16* __restrict__ prev,
                                             const float* __restrict__ attn,
                                             float* __restrict__ o2)
{
    int idx = blockIdx.x * 256 + threadIdx.x;
    int j = idx & 31, i = (idx >> 5) & 31;
    int oc = (idx >> 10) & (OC - 1);
    int b = idx >> 17;
    const bf16* pl = prev + ((size_t)b * OC + oc) * HW;
    const float* at = attn + (size_t)b * HW;
    float v = roi_bin([&](int y, int x) {
        int p = y * Ww + x;
        return __bfloat162float(pl[p]) * at[p];
    }, i, j);
    o2[idx] = v;
}

// out0 = roi_align(l2) + aux + bo2 + bo3
__global__ __launch_bounds__(256) void final_k(const bf16* __restrict__ l2,
                                               const float* __restrict__ aux,
                                               const float* __restrict__ bo2,
                                               const float* __restrict__ bo3,
                                               float* __restrict__ o0)
{
    int idx = blockIdx.x * 256 + threadIdx.x;
    int j = idx & 31, i = (idx >> 5) & 31;
    int oc = (idx >> 10) & (OC - 1);
    int b = idx >> 17;
    const bf16* pl = l2 + ((size_t)b * OC + oc) * HW;
    float r = roi_bin([&](int y, int x) {
        return __bfloat162float(pl[y * Ww + x]);
    }, i, j);
    o0[idx] = r + aux[idx] + bo2[idx] + bo3[idx];
}

// ---------------- launch ----------------
extern "C" void kernel_launch(void* const* d_in, const int* in_sizes, int n_in,
                              void* d_out, int out_size, void* d_ws, size_t ws_size,
                              hipStream_t stream)
{
    const float* out1  = (const float*)d_in[0];
    const float* out2  = (const float*)d_in[1];
    const float* out3  = (const float*)d_in[2];
    const float* w1    = (const float*)d_in[3];  const float* b1    = (const float*)d_in[4];
    const float* w2    = (const float*)d_in[5];  const float* b2    = (const float*)d_in[6];
    const float* w3    = (const float*)d_in[7];  const float* b3    = (const float*)d_in[8];
    const float* w_aux = (const float*)d_in[9];  const float* b_aux = (const float*)d_in[10];
    const float* w_b2  = (const float*)d_in[11]; const float* b_b2  = (const float*)d_in[12];
    const float* w_prev= (const float*)d_in[13]; const float* b_prev= (const float*)d_in[14];
    const float* lin_w = (const float*)d_in[15]; const float* lin_b = (const float*)d_in[16];

    char* ws = (char*)d_ws;
    bf16*  l1   = (bf16*)(ws);                    // 32*128*4096 bf16 = 33,554,432 B
    bf16*  l2   = (bf16*)(ws + 33554432);
    bf16*  l3   = (bf16*)(ws + 67108864);         // reused as `prev` after aux conv
    float* aux  = (float*)(ws + 100663296);       // 16,777,216 B
    float* attn = (float*)(ws + 117440512);       // 524,288 B
    bf16*  prevb = l3;

    float* o0 = (float*)d_out;
    float* o1 = o0 + (size_t)B * OC * 32 * 32;    // block_out2
    float* o2 = o1 + (size_t)B * OC * 32 * 32;    // block_out3

    dim3 cblk(64);
    // attention (independent of conv chain)
    attn_k<<<dim3(B), dim3(256), 0, stream>>>(out1, lin_w, lin_b, attn);
    // l1 = lrelu(conv(out1, w1))
    conv3x3_k<float, bf16, 64, 0, 1><<<dim3(64, OC / OCPB, B), cblk, 0, stream>>>(out1, out1, w1, b1, l1);
    // l2 = lrelu(conv(l1, w2))
    conv3x3_k<bf16, bf16, 128, 0, 1><<<dim3(64, OC / OCPB, B), cblk, 0, stream>>>(l1, l1, w2, b2, l2);
    // l3 = lrelu(conv(l2, w3))
    conv3x3_k<bf16, bf16, 128, 0, 1><<<dim3(64, OC / OCPB, B), cblk, 0, stream>>>(l2, l2, w3, b3, l3);
    // aux = lrelu(conv(l3, w_aux, stride2))
    conv3x3_k<bf16, float, 128, 0, 2><<<dim3(16, OC / OCPB, B), cblk, 0, stream>>>(l3, l3, w_aux, b_aux, aux);
    // block_out2 = lrelu(conv(concat(l1,l2), w_b2, stride2)) -> o1
    conv3x3_k<bf16, float, 128, 128, 2><<<dim3(16, OC / OCPB, B), cblk, 0, stream>>>(l1, l2, w_b2, b_b2, o1);
    // prev = lrelu(conv(concat(out2,out3), w_prev)) -> reuse l3 slot (aux already consumed l3)
    conv3x3_k<float, bf16, 64, 64, 1><<<dim3(64, OC / OCPB, B), cblk, 0, stream>>>(out2, out3, w_prev, b_prev, prevb);
    // block_out3 = roi(prev * attn) -> o2
    bo3_k<<<dim3((B * OC * 1024) / 256), dim3(256), 0, stream>>>(prevb, attn, o2);
    // out0 = roi(l2) + aux + bo2 + bo3
    final_k<<<dim3((B * OC * 1024) / 256), dim3(256), 0, stream>>>(l2, aux, o1, o2, o0);
}

// Round 2
// 1476.478 us; speedup vs baseline: 3.2065x; 3.2065x over previous
//
#include <hip/hip_runtime.h>
#include <hip/hip_bf16.h>

typedef __attribute__((ext_vector_type(8))) short short8;
typedef __attribute__((ext_vector_type(4))) float f32x4;

constexpr int B = 32, C = 64, HW = 4096;

__device__ __forceinline__ unsigned short f2bf(float f) {
    __hip_bfloat16 h = __float2bfloat16(f);
    unsigned short u; __builtin_memcpy(&u, &h, 2); return u;
}
__device__ __forceinline__ float b2f(unsigned short u) {
    unsigned int t = ((unsigned int)u) << 16; float f; __builtin_memcpy(&f, &t, 4); return f;
}

// ---------------- attention: logits then softmax ----------------
__global__ __launch_bounds__(256) void logits_k(const float* __restrict__ out1,
                                                const float* __restrict__ lin_w,
                                                const float* __restrict__ lin_b,
                                                float* __restrict__ logits)
{
    int b = blockIdx.x >> 4;
    int p = (blockIdx.x & 15) * 256 + threadIdx.x;
    float acc = lin_b[p];
    const float* xb = out1 + (size_t)b * C * HW + p;
    const float* wp = lin_w + (size_t)p * C;
#pragma unroll
    for (int c = 0; c < C; c += 4) {
        float4 w4 = *(const float4*)(wp + c);
        acc = fmaf(xb[(size_t)c * HW],       w4.x, acc);
        acc = fmaf(xb[(size_t)(c + 1) * HW], w4.y, acc);
        acc = fmaf(xb[(size_t)(c + 2) * HW], w4.z, acc);
        acc = fmaf(xb[(size_t)(c + 3) * HW], w4.w, acc);
    }
    logits[(size_t)b * HW + p] = acc;
}

__global__ __launch_bounds__(256) void softmax_k(const float* __restrict__ logits,
                                                 float* __restrict__ attn)
{
    int b = blockIdx.x, tid = threadIdx.x;
    float lg[16];
#pragma unroll
    for (int k = 0; k < 16; ++k) lg[k] = logits[(size_t)b * HW + tid + (k << 8)];
    __shared__ float red[256];
    float m = -INFINITY;
#pragma unroll
    for (int k = 0; k < 16; ++k) m = fmaxf(m, lg[k]);
    red[tid] = m; __syncthreads();
    for (int s = 128; s > 0; s >>= 1) {
        if (tid < s) red[tid] = fmaxf(red[tid], red[tid + s]);
        __syncthreads();
    }
    m = red[0]; __syncthreads();
    float se = 0.f;
#pragma unroll
    for (int k = 0; k < 16; ++k) { lg[k] = __expf(lg[k] - m); se += lg[k]; }
    red[tid] = se; __syncthreads();
    for (int s = 128; s > 0; s >>= 1) {
        if (tid < s) red[tid] += red[tid + s];
        __syncthreads();
    }
    float inv = 1.0f / red[0];
#pragma unroll
    for (int k = 0; k < 16; ++k)
        attn[(size_t)b * HW + tid + (k << 8)] = lg[k] * inv;
}

// ---------------- weight prep: w[oc][ic][3][3] f32 -> wT[kk][oc][ic] bf16 ----------------
__global__ __launch_bounds__(256) void wprep_k(const float* w1, const float* w2, const float* w3,
                                               const float* wa, const float* wb2, const float* wp,
                                               unsigned short* __restrict__ wT)
{
    int blk = blockIdx.x;
    int base, ic, l2ic, off; const float* src;
    if      (blk < 32)  { base = 0;   ic = 64;  l2ic = 6; off = 0;      src = w1;  }
    else if (blk < 96)  { base = 32;  ic = 128; l2ic = 7; off = 73728;  src = w2;  }
    else if (blk < 160) { base = 96;  ic = 128; l2ic = 7; off = 221184; src = w3;  }
    else if (blk < 224) { base = 160; ic = 128; l2ic = 7; off = 368640; src = wa;  }
    else if (blk < 352) { base = 224; ic = 256; l2ic = 8; off = 516096; src = wb2; }
    else                { base = 352; ic = 128; l2ic = 7; off = 811008; src = wp;  }
    int pair = (blk - base) * 256 + threadIdx.x;
    int oc = pair >> l2ic, icx = pair & (ic - 1);
    const float* s = src + ((size_t)(oc * ic + icx)) * 9;
#pragma unroll
    for (int k = 0; k < 9; ++k)
        wT[(size_t)off + ((size_t)(k * 128 + oc)) * ic + icx] = f2bf(s[k]);
}

// ---------------- MFMA implicit-GEMM 3x3 conv ----------------
// MODE 0: NHWC bf16 src0 (pixel stride PS_IN, channel offset CO_IN)
// MODE 1: NCHW f32 src0 (C=64); MODE 2: NCHW f32 dual src0/src1 (64+64)
template<int IC, int STRIDE, int MODE, int PS_IN, int CO_IN, int OPS, int OCO, bool ATTN>
__global__ __launch_bounds__(256) void conv_k(const void* __restrict__ src0,
                                              const void* __restrict__ src1,
                                              const unsigned short* __restrict__ wT,
                                              const float* __restrict__ bias,
                                              const float* __restrict__ attn,
                                              unsigned short* __restrict__ out)
{
    constexpr int ICT = (IC > 128) ? 128 : IC;    // channels per LDS phase
    constexpr int PHASES = IC / ICT;
    constexpr int NCH = ICT / 8;                  // 16B chunks per pixel row
    constexpr int ROWB = ICT * 2;
    constexpr int WO = 64 / STRIDE;
    constexpr int NFN = (STRIDE == 1) ? 8 : 4;    // n-frags per wave

    __shared__ f32x4 smem4[3 * 66 * ICT * 2 / 16];
    char* smem = (char*)smem4;

    int t = threadIdx.x, y = blockIdx.x, b = blockIdx.y;
    int wave = t >> 6, lane = t & 63;
    int yin0 = y * STRIDE - 1;

    // zero-fill (covers px=0/65 columns and OOB rows)
    constexpr int ZTOT = 3 * 66 * ICT * 2 / 16;
    for (int i = t; i < ZTOT; i += 256) smem4[i] = (f32x4)0.0f;

    f32x4 acc[NFN];
#pragma unroll
    for (int j = 0; j < NFN; ++j) acc[j] = (f32x4)0.0f;

    int mpx, nf0;
    if constexpr (STRIDE == 1) { mpx = wave * 16 + (lane & 15); nf0 = 0; }
    else                       { mpx = (wave & 1) * 16 + (lane & 15); nf0 = (wave >> 1) * 4; }

    for (int phase = 0; phase < PHASES; ++phase) {
        __syncthreads();   // zero-fill done / previous phase reads done
        // ---- stage A tile: rows yin0..yin0+2, px 0..63 -> lds px 1..64, swizzled ----
        if constexpr (MODE == 0) {
            const unsigned short* in = (const unsigned short*)src0;
            constexpr int TOT = 3 * 64 * NCH;
            for (int i = t; i < TOT; i += 256) {
                int ch8 = i & (NCH - 1);
                int px = (i / NCH) & 63;
                int r = i / (NCH * 64);
                int yin = yin0 + r;
                if ((unsigned)yin < 64u) {
                    const unsigned short* g = in + ((size_t)(b * HW + yin * 64 + px)) * PS_IN
                                              + CO_IN + phase * 128 + ch8 * 8;
                    short8 v = *(const short8*)g;
                    int pl = px + 1;
                    int byte_off = (r * 66 + pl) * ROWB + ((ch8 ^ (pl & 7)) * 16);
                    *(short8*)(smem + byte_off) = v;
                }
            }
        } else {
            constexpr int TOTQ = 3 * ICT * 16;
            for (int i = t; i < TOTQ; i += 256) {
                int pq = i & 15;
                int c = (i >> 4) & (ICT - 1);
                int r = i / (16 * ICT);
                int yin = yin0 + r;
                if ((unsigned)yin < 64u) {
                    const float* plane;
                    if constexpr (MODE == 1)
                        plane = (const float*)src0 + (size_t)(b * 64 + c) * HW;
                    else
                        plane = (c < 64) ? (const float*)src0 + (size_t)(b * 64 + c) * HW
                                         : (const float*)src1 + (size_t)(b * 64 + (c - 64)) * HW;
                    float4 v4 = *(const float4*)(plane + yin * 64 + pq * 4);
                    float vv[4] = {v4.x, v4.y, v4.z, v4.w};
#pragma unroll
                    for (int k = 0; k < 4; ++k) {
                        int pl = pq * 4 + k + 1;
                        int byte_off = (r * 66 + pl) * ROWB + (((c >> 3) ^ (pl & 7)) * 16) + (c & 7) * 2;
                        *(unsigned short*)(smem + byte_off) = f2bf(vv[k]);
                    }
                }
            }
        }
        __syncthreads();
        // ---- main loop: per k-step 1 ds_read (A) + NFN global B + NFN MFMA ----
        for (int icg = 0; icg < ICT / 32; ++icg) {
#pragma unroll
            for (int kk = 0; kk < 9; ++kk) {
                int ky = kk / 3, kx = kk % 3;
                int pl = mpx * STRIDE + kx;
                int chunk = icg * 4 + (lane >> 4);
                int abyte = (ky * 66 + pl) * ROWB + ((chunk ^ (pl & 7)) * 16);
                short8 a = *(const short8*)(smem + abyte);
                const unsigned short* wbase = wT + ((size_t)(kk * 128 + (lane & 15))) * IC
                                              + phase * 128 + icg * 32 + (lane >> 4) * 8;
#pragma unroll
                for (int j = 0; j < NFN; ++j) {
                    short8 bb = *(const short8*)(wbase + (size_t)((nf0 + j) * 16) * IC);
                    acc[j] = __builtin_amdgcn_mfma_f32_16x16x32_bf16(a, bb, acc[j], 0, 0, 0);
                }
            }
        }
    }
    // ---- epilogue: bias + lrelu (+attn) -> NHWC bf16 ----
    int mbase = (STRIDE == 1) ? wave * 16 : (wave & 1) * 16;
    int prow = (lane >> 4) * 4;
    float attnv[4];
    if constexpr (ATTN) {
#pragma unroll
        for (int r = 0; r < 4; ++r)
            attnv[r] = attn[(size_t)b * HW + y * 64 + mbase + prow + r];
    }
#pragma unroll
    for (int j = 0; j < NFN; ++j) {
        int oc = (nf0 + j) * 16 + (lane & 15);
        float bs = bias[oc];
#pragma unroll
        for (int r = 0; r < 4; ++r) {
            int px = mbase + prow + r;
            float v = acc[j][r] + bs;
            v = (v >= 0.0f) ? v : 0.1f * v;
            if constexpr (ATTN) v *= attnv[r];
            out[((size_t)(b * WO * WO + y * WO + px)) * OPS + OCO + oc] = f2bf(v);
        }
    }
}

// ---------------- fused RoI + combine ----------------
__device__ __forceinline__ void acc8(float* a, const unsigned short* p, float w) {
    short8 v = *(const short8*)p;
#pragma unroll
    for (int k = 0; k < 8; ++k) a[k] = fmaf(w, b2f((unsigned short)v[k]), a[k]);
}

__global__ __launch_bounds__(256) void fuse_roi_k(const unsigned short* __restrict__ prevs,
                                                  const unsigned short* __restrict__ l12,
                                                  const unsigned short* __restrict__ auxb,
                                                  const unsigned short* __restrict__ bo2b,
                                                  float* __restrict__ o0,
                                                  float* __restrict__ o1,
                                                  float* __restrict__ o2)
{
    int idx = blockIdx.x * 256 + threadIdx.x;
    int j = idx & 31, i = (idx >> 5) & 31, ocg = (idx >> 10) & 15, b = idx >> 14;
    float a3[8] = {0,0,0,0,0,0,0,0}, aR[8] = {0,0,0,0,0,0,0,0};
    const unsigned short* pb = prevs + (size_t)b * HW * 128 + ocg * 8;
    const unsigned short* lb = l12 + (size_t)b * HW * 256 + 128 + ocg * 8;
#pragma unroll
    for (int sy = 0; sy < 2; ++sy) {
        float ys = (i + 0.25f + 0.5f * sy) * 1.96875f;
        int y0 = (int)ys;
        int y1 = min(y0 + 1, 63);
        float ly = ys - (float)y0, hy = 1.0f - ly;
#pragma unroll
        for (int sx = 0; sx < 2; ++sx) {
            float xs = (j + 0.25f + 0.5f * sx) * 1.96875f;
            int x0 = (int)xs;
            int x1 = min(x0 + 1, 63);
            float lx = xs - (float)x0, hx = 1.0f - lx;
            int p00 = y0 * 64 + x0, p01 = y0 * 64 + x1, p10 = y1 * 64 + x0, p11 = y1 * 64 + x1;
            float w00 = hy * hx, w01 = hy * lx, w10 = ly * hx, w11 = ly * lx;
            acc8(a3, pb + (size_t)p00 * 128, w00); acc8(a3, pb + (size_t)p01 * 128, w01);
            acc8(a3, pb + (size_t)p10 * 128, w10); acc8(a3, pb + (size_t)p11 * 128, w11);
            acc8(aR, lb + (size_t)p00 * 256, w00); acc8(aR, lb + (size_t)p01 * 256, w01);
            acc8(aR, lb + (size_t)p10 * 256, w10); acc8(aR, lb + (size_t)p11 * 256, w11);
        }
    }
    int p32 = i * 32 + j;
    const unsigned short* ax = auxb + ((size_t)(b * 1024 + p32)) * 128 + ocg * 8;
    const unsigned short* b2 = bo2b + ((size_t)(b * 1024 + p32)) * 128 + ocg * 8;
#pragma unroll
    for (int k = 0; k < 8; ++k) {
        int oc = ocg * 8 + k;
        size_t ob = ((size_t)(b * 128 + oc)) * 1024 + p32;
        float v3 = a3[k] * 0.25f;
        float v2 = b2f(b2[k]);
        o2[ob] = v3;
        o1[ob] = v2;
        o0[ob] = aR[k] * 0.25f + b2f(ax[k]) + v2 + v3;
    }
}

// ---------------- launch ----------------
extern "C" void kernel_launch(void* const* d_in, const int* in_sizes, int n_in,
                              void* d_out, int out_size, void* d_ws, size_t ws_size,
                              hipStream_t stream)
{
    const float* out1  = (const float*)d_in[0];
    const float* out2  = (const float*)d_in[1];
    const float* out3  = (const float*)d_in[2];
    const float* w1    = (const float*)d_in[3];  const float* b1    = (const float*)d_in[4];
    const float* w2    = (const float*)d_in[5];  const float* b2    = (const float*)d_in[6];
    const float* w3    = (const float*)d_in[7];  const float* b3    = (const float*)d_in[8];
    const float* w_aux = (const float*)d_in[9];  const float* b_aux = (const float*)d_in[10];
    const float* w_b2  = (const float*)d_in[11]; const float* b_b2  = (const float*)d_in[12];
    const float* w_prev= (const float*)d_in[13]; const float* b_prev= (const float*)d_in[14];
    const float* lin_w = (const float*)d_in[15]; const float* lin_b = (const float*)d_in[16];

    char* ws = (char*)d_ws;
    unsigned short* l12cat = (unsigned short*)(ws);                 // [B][4096][256] bf16, 64 MB
    unsigned short* l3     = (unsigned short*)(ws + 67108864);      // [B][4096][128] bf16, 32 MB
    unsigned short* prevs  = l3;                                     // reused after aux conv
    unsigned short* auxb   = (unsigned short*)(ws + 100663296);     // [B][1024][128] bf16, 8 MB
    unsigned short* bo2b   = (unsigned short*)(ws + 109051904);     // [B][1024][128] bf16, 8 MB
    float* attn   = (float*)(ws + 117440512);                        // 512 KB
    float* logits = (float*)(ws + 117964800);                        // 512 KB
    unsigned short* wT = (unsigned short*)(ws + 118489088);          // 1.92 MB

    float* o0 = (float*)d_out;
    float* o1 = o0 + (size_t)B * 128 * 1024;
    float* o2 = o1 + (size_t)B * 128 * 1024;

    wprep_k<<<dim3(416), dim3(256), 0, stream>>>(w1, w2, w3, w_aux, w_b2, w_prev, wT);
    logits_k<<<dim3(B * 16), dim3(256), 0, stream>>>(out1, lin_w, lin_b, logits);
    softmax_k<<<dim3(B), dim3(256), 0, stream>>>(logits, attn);

    // l1 = lrelu(conv(out1,w1)) -> l12cat ch 0..127
    conv_k<64, 1, 1, 0, 0, 256, 0, false><<<dim3(64, B), dim3(256), 0, stream>>>(
        out1, nullptr, wT + 0, b1, nullptr, l12cat);
    // l2 = lrelu(conv(l1,w2)) -> l12cat ch 128..255
    conv_k<128, 1, 0, 256, 0, 256, 128, false><<<dim3(64, B), dim3(256), 0, stream>>>(
        l12cat, nullptr, wT + 73728, b2, nullptr, l12cat);
    // l3 = lrelu(conv(l2,w3))
    conv_k<128, 1, 0, 256, 128, 128, 0, false><<<dim3(64, B), dim3(256), 0, stream>>>(
        l12cat, nullptr, wT + 221184, b3, nullptr, l3);
    // aux = lrelu(conv(l3,w_aux,s2))
    conv_k<128, 2, 0, 128, 0, 128, 0, false><<<dim3(32, B), dim3(256), 0, stream>>>(
        l3, nullptr, wT + 368640, b_aux, nullptr, auxb);
    // block_out2 = lrelu(conv(concat(l1,l2),w_b2,s2))
    conv_k<256, 2, 0, 256, 0, 128, 0, false><<<dim3(32, B), dim3(256), 0, stream>>>(
        l12cat, nullptr, wT + 516096, b_b2, nullptr, bo2b);
    // prevs = lrelu(conv(concat(out2,out3),w_prev)) * attn   (overwrites l3 slot)
    conv_k<128, 1, 2, 0, 0, 128, 0, true><<<dim3(64, B), dim3(256), 0, stream>>>(
        out2, out3, wT + 811008, b_prev, attn, prevs);

    fuse_roi_k<<<dim3(2048), dim3(256), 0, stream>>>(prevs, l12cat, auxb, bo2b, o0, o1, o2);
}

// Round 3
// 686.048 us; speedup vs baseline: 6.9009x; 2.1522x over previous
//
#include <hip/hip_runtime.h>
#include <hip/hip_bf16.h>

typedef __attribute__((ext_vector_type(8))) short short8;
typedef __attribute__((ext_vector_type(4))) float f32x4;

constexpr int B = 32, C = 64, HW = 4096;

__device__ __forceinline__ unsigned short f2bf(float f) {
    __hip_bfloat16 h = __float2bfloat16(f);
    unsigned short u; __builtin_memcpy(&u, &h, 2); return u;
}
__device__ __forceinline__ float b2f(unsigned short u) {
    unsigned int t = ((unsigned int)u) << 16; float f; __builtin_memcpy(&f, &t, 4); return f;
}
__device__ __forceinline__ void gllds16(const void* g, void* l) {
    __builtin_amdgcn_global_load_lds((const __attribute__((address_space(1))) unsigned int*)g,
                                     (__attribute__((address_space(3))) unsigned int*)l, 16, 0, 0);
}

// ---------------- NCHW f32 -> NHWC bf16 transpose ----------------
__global__ __launch_bounds__(256) void tr_k(const float* __restrict__ out1,
                                            const float* __restrict__ out2,
                                            const float* __restrict__ out3,
                                            unsigned short* __restrict__ t1,
                                            unsigned short* __restrict__ tp)
{
    int t = threadIdx.x;
    int px = blockIdx.x * 256 + t;
    int b = blockIdx.y;
    if (blockIdx.z == 0) {
        const float* src = out1 + (size_t)b * 64 * HW + px;
        unsigned short v[64];
#pragma unroll
        for (int c = 0; c < 64; ++c) v[c] = f2bf(src[(size_t)c * HW]);
        unsigned short* dst = t1 + ((size_t)b * HW + px) * 64;
#pragma unroll
        for (int j = 0; j < 8; ++j)
            *(short8*)(dst + j * 8) = *(short8*)(v + j * 8);
    } else {
        const float* s2 = out2 + (size_t)b * 64 * HW + px;
        const float* s3 = out3 + (size_t)b * 64 * HW + px;
        unsigned short v[128];
#pragma unroll
        for (int c = 0; c < 64; ++c) v[c] = f2bf(s2[(size_t)c * HW]);
#pragma unroll
        for (int c = 0; c < 64; ++c) v[64 + c] = f2bf(s3[(size_t)c * HW]);
        unsigned short* dst = tp + ((size_t)b * HW + px) * 128;
#pragma unroll
        for (int j = 0; j < 16; ++j)
            *(short8*)(dst + j * 8) = *(short8*)(v + j * 8);
    }
}

// ---------------- attention: logits then softmax ----------------
__global__ __launch_bounds__(256) void logits_k(const float* __restrict__ out1,
                                                const float* __restrict__ lin_w,
                                                const float* __restrict__ lin_b,
                                                float* __restrict__ logits)
{
    int b = blockIdx.x >> 4;
    int p = (blockIdx.x & 15) * 256 + threadIdx.x;
    float acc = lin_b[p];
    const float* xb = out1 + (size_t)b * C * HW + p;
    const float* wp = lin_w + (size_t)p * C;
#pragma unroll
    for (int c = 0; c < C; c += 4) {
        float4 w4 = *(const float4*)(wp + c);
        acc = fmaf(xb[(size_t)c * HW],       w4.x, acc);
        acc = fmaf(xb[(size_t)(c + 1) * HW], w4.y, acc);
        acc = fmaf(xb[(size_t)(c + 2) * HW], w4.z, acc);
        acc = fmaf(xb[(size_t)(c + 3) * HW], w4.w, acc);
    }
    logits[(size_t)b * HW + p] = acc;
}

__global__ __launch_bounds__(256) void softmax_k(const float* __restrict__ logits,
                                                 float* __restrict__ attn)
{
    int b = blockIdx.x, tid = threadIdx.x;
    float lg[16];
#pragma unroll
    for (int k = 0; k < 16; ++k) lg[k] = logits[(size_t)b * HW + tid + (k << 8)];
    __shared__ float red[256];
    float m = -INFINITY;
#pragma unroll
    for (int k = 0; k < 16; ++k) m = fmaxf(m, lg[k]);
    red[tid] = m; __syncthreads();
    for (int s = 128; s > 0; s >>= 1) {
        if (tid < s) red[tid] = fmaxf(red[tid], red[tid + s]);
        __syncthreads();
    }
    m = red[0]; __syncthreads();
    float se = 0.f;
#pragma unroll
    for (int k = 0; k < 16; ++k) { lg[k] = __expf(lg[k] - m); se += lg[k]; }
    red[tid] = se; __syncthreads();
    for (int s = 128; s > 0; s >>= 1) {
        if (tid < s) red[tid] += red[tid + s];
        __syncthreads();
    }
    float inv = 1.0f / red[0];
#pragma unroll
    for (int k = 0; k < 16; ++k)
        attn[(size_t)b * HW + tid + (k << 8)] = lg[k] * inv;
}

// ---------------- weight prep: w[oc][ic][3][3] f32 -> wT[kk][oc][ic] bf16 ----------------
__global__ __launch_bounds__(256) void wprep_k(const float* w1, const float* w2, const float* w3,
                                               const float* wa, const float* wb2, const float* wp,
                                               unsigned short* __restrict__ wT)
{
    int blk = blockIdx.x;
    int base, ic, l2ic, off; const float* src;
    if      (blk < 32)  { base = 0;   ic = 64;  l2ic = 6; off = 0;      src = w1;  }
    else if (blk < 96)  { base = 32;  ic = 128; l2ic = 7; off = 73728;  src = w2;  }
    else if (blk < 160) { base = 96;  ic = 128; l2ic = 7; off = 221184; src = w3;  }
    else if (blk < 224) { base = 160; ic = 128; l2ic = 7; off = 368640; src = wa;  }
    else if (blk < 352) { base = 224; ic = 256; l2ic = 8; off = 516096; src = wb2; }
    else                { base = 352; ic = 128; l2ic = 7; off = 811008; src = wp;  }
    int pair = (blk - base) * 256 + threadIdx.x;
    int oc = pair >> l2ic, icx = pair & (ic - 1);
    const float* s = src + ((size_t)(oc * ic + icx)) * 9;
#pragma unroll
    for (int k = 0; k < 9; ++k)
        wT[(size_t)off + ((size_t)(k * 128 + oc)) * ic + icx] = f2bf(s[k]);
}

// ---------------- MFMA implicit-GEMM 3x3 conv: A direct-global, B LDS double-buffered ----------------
template<int IC, int STRIDE, int PS_IN, int CO_IN, int OPS, int OCO, bool ATTN>
__global__ __launch_bounds__(256, 4) void conv_k(
    const unsigned short* __restrict__ in,     // NHWC bf16
    const unsigned short* __restrict__ wTc,    // [9][128][IC] bf16
    const float* __restrict__ bias,
    const float* __restrict__ attn,
    unsigned short* __restrict__ out)
{
    constexpr int NICG = IC / 32;
    constexpr int L = (IC == 64) ? 1 : (IC == 128) ? 2 : 3;
    constexpr int NS = 9 * NICG;
    constexpr int NPX = (STRIDE == 1) ? 4096 : 1024;
    constexpr int WO = (STRIDE == 1) ? 64 : 32;

    __shared__ char bsm[2][8192];

    int t = threadIdx.x;
    int wave = t >> 6, lane = t & 63;
    int mw = wave & 1, nw = wave >> 1;
    int l15 = lane & 15, lc = lane >> 4;
    int y0 = blockIdx.x, b = blockIdx.y;

    // B LDS read byte-offsets (swizzled: slot c' = c ^ ((oc>>1)&3))
    int bofs[4];
#pragma unroll
    for (int nf = 0; nf < 4; ++nf) {
        int oc = nw * 64 + nf * 16 + l15;
        bofs[nf] = oc * 64 + ((lc ^ ((oc >> 1) & 3)) << 4);
    }
    // staging source (thread t fills LDS slot t and slot 256+t; inverse-swizzled src)
    int oc0 = t >> 2;
    int c0 = (t & 3) ^ ((oc0 >> 1) & 3);
    const unsigned short* wsrc = wTc + oc0 * IC + c0 * 8;
    char* lbase = &bsm[0][0] + (wave << 10);

    const unsigned short* base_b = in + (size_t)b * HW * PS_IN + CO_IN + (lc << 3);
    int col[2];
#pragma unroll
    for (int f = 0; f < 2; ++f)
        col[f] = (STRIDE == 1) ? (mw * 32 + f * 16 + l15) : (f * 16 + l15);

    f32x4 acc[2][4];
#pragma unroll
    for (int f = 0; f < 2; ++f)
#pragma unroll
        for (int nf = 0; nf < 4; ++nf) acc[f][nf] = (f32x4)0.0f;

    auto stage = [&](int s, int buf) {
        int kk = s >> L, icg = s & (NICG - 1);
        const unsigned short* p = wsrc + (size_t)kk * 128 * IC + icg * 32;
        char* d = lbase + buf * 8192;
        gllds16(p, d);
        gllds16(p + 64 * IC, d + 4096);
    };

    stage(0, 0);
    __syncthreads();

    for (int s = 0; s < NS; ++s) {
        int cur = s & 1;
        if (s + 1 < NS) stage(s + 1, cur ^ 1);
        int kk = s >> L, icg = s & (NICG - 1);
        int ky = (kk * 11) >> 5;
        int kx = kk - ky * 3;
        int iy = (STRIDE == 1) ? (y0 + ky - 1) : ((y0 * 2 + mw) * 2 + ky - 1);
        bool yok = (unsigned)iy < 64u;
        const unsigned short* prow = base_b + (long)iy * (64 * PS_IN) + icg * 32;
        short8 az = {0, 0, 0, 0, 0, 0, 0, 0};
        short8 aa[2];
#pragma unroll
        for (int f = 0; f < 2; ++f) {
            int ix = (STRIDE == 1) ? (col[f] + kx - 1) : (2 * col[f] + kx - 1);
            bool ok = yok && ((unsigned)ix < 64u);
            const short8* ap = (const short8*)(prow + (long)ix * PS_IN);
            aa[f] = ok ? *ap : az;
        }
        const char* bb_base = &bsm[0][0] + cur * 8192;
        short8 bb[4];
#pragma unroll
        for (int nf = 0; nf < 4; ++nf)
            bb[nf] = *(const short8*)(bb_base + bofs[nf]);
#pragma unroll
        for (int f = 0; f < 2; ++f)
#pragma unroll
            for (int nf = 0; nf < 4; ++nf)
                acc[f][nf] = __builtin_amdgcn_mfma_f32_16x16x32_bf16(aa[f], bb[nf], acc[f][nf], 0, 0, 0);
        __syncthreads();
    }

    // epilogue: bias + lrelu (+attn) -> NHWC bf16
    int orow = (STRIDE == 1) ? y0 : (y0 * 2 + mw);
    float bs[4];
#pragma unroll
    for (int nf = 0; nf < 4; ++nf) bs[nf] = bias[nw * 64 + nf * 16 + l15];
#pragma unroll
    for (int f = 0; f < 2; ++f) {
#pragma unroll
        for (int r = 0; r < 4; ++r) {
            int pxcol = ((STRIDE == 1) ? mw * 32 : 0) + f * 16 + (lc << 2) + r;
            float av = 1.0f;
            if constexpr (ATTN) av = attn[(size_t)b * HW + y0 * 64 + pxcol];
            size_t obase = ((size_t)b * NPX + (size_t)orow * WO + pxcol) * OPS + OCO;
#pragma unroll
            for (int nf = 0; nf < 4; ++nf) {
                int oc = nw * 64 + nf * 16 + l15;
                float v = acc[f][nf][r] + bs[nf];
                v = (v >= 0.0f) ? v : 0.1f * v;
                if constexpr (ATTN) v *= av;
                out[obase + oc] = f2bf(v);
            }
        }
    }
}

// ---------------- fused RoI + combine ----------------
__device__ __forceinline__ void acc8(float* a, const unsigned short* p, float w) {
    short8 v = *(const short8*)p;
#pragma unroll
    for (int k = 0; k < 8; ++k) a[k] = fmaf(w, b2f((unsigned short)v[k]), a[k]);
}

__global__ __launch_bounds__(256) void fuse_roi_k(const unsigned short* __restrict__ prevs,
                                                  const unsigned short* __restrict__ l12,
                                                  const unsigned short* __restrict__ auxb,
                                                  const unsigned short* __restrict__ bo2b,
                                                  float* __restrict__ o0,
                                                  float* __restrict__ o1,
                                                  float* __restrict__ o2)
{
    int idx = blockIdx.x * 256 + threadIdx.x;
    int j = idx & 31, i = (idx >> 5) & 31, ocg = (idx >> 10) & 15, b = idx >> 14;
    float a3[8] = {0,0,0,0,0,0,0,0}, aR[8] = {0,0,0,0,0,0,0,0};
    const unsigned short* pb = prevs + (size_t)b * HW * 128 + ocg * 8;
    const unsigned short* lb = l12 + (size_t)b * HW * 256 + 128 + ocg * 8;
#pragma unroll
    for (int sy = 0; sy < 2; ++sy) {
        float ys = (i + 0.25f + 0.5f * sy) * 1.96875f;
        int y0 = (int)ys;
        int y1 = min(y0 + 1, 63);
        float ly = ys - (float)y0, hy = 1.0f - ly;
#pragma unroll
        for (int sx = 0; sx < 2; ++sx) {
            float xs = (j + 0.25f + 0.5f * sx) * 1.96875f;
            int x0 = (int)xs;
            int x1 = min(x0 + 1, 63);
            float lx = xs - (float)x0, hx = 1.0f - lx;
            int p00 = y0 * 64 + x0, p01 = y0 * 64 + x1, p10 = y1 * 64 + x0, p11 = y1 * 64 + x1;
            float w00 = hy * hx, w01 = hy * lx, w10 = ly * hx, w11 = ly * lx;
            acc8(a3, pb + (size_t)p00 * 128, w00); acc8(a3, pb + (size_t)p01 * 128, w01);
            acc8(a3, pb + (size_t)p10 * 128, w10); acc8(a3, pb + (size_t)p11 * 128, w11);
            acc8(aR, lb + (size_t)p00 * 256, w00); acc8(aR, lb + (size_t)p01 * 256, w01);
            acc8(aR, lb + (size_t)p10 * 256, w10); acc8(aR, lb + (size_t)p11 * 256, w11);
        }
    }
    int p32 = i * 32 + j;
    const unsigned short* ax = auxb + ((size_t)(b * 1024 + p32)) * 128 + ocg * 8;
    const unsigned short* b2 = bo2b + ((size_t)(b * 1024 + p32)) * 128 + ocg * 8;
#pragma unroll
    for (int k = 0; k < 8; ++k) {
        int oc = ocg * 8 + k;
        size_t ob = ((size_t)(b * 128 + oc)) * 1024 + p32;
        float v3 = a3[k] * 0.25f;
        float v2 = b2f(b2[k]);
        o2[ob] = v3;
        o1[ob] = v2;
        o0[ob] = aR[k] * 0.25f + b2f(ax[k]) + v2 + v3;
    }
}

// ---------------- launch ----------------
extern "C" void kernel_launch(void* const* d_in, const int* in_sizes, int n_in,
                              void* d_out, int out_size, void* d_ws, size_t ws_size,
                              hipStream_t stream)
{
    const float* out1  = (const float*)d_in[0];
    const float* out2  = (const float*)d_in[1];
    const float* out3  = (const float*)d_in[2];
    const float* w1    = (const float*)d_in[3];  const float* b1    = (const float*)d_in[4];
    const float* w2    = (const float*)d_in[5];  const float* b2    = (const float*)d_in[6];
    const float* w3    = (const float*)d_in[7];  const float* b3    = (const float*)d_in[8];
    const float* w_aux = (const float*)d_in[9];  const float* b_aux = (const float*)d_in[10];
    const float* w_b2  = (const float*)d_in[11]; const float* b_b2  = (const float*)d_in[12];
    const float* w_prev= (const float*)d_in[13]; const float* b_prev= (const float*)d_in[14];
    const float* lin_w = (const float*)d_in[15]; const float* lin_b = (const float*)d_in[16];

    char* ws = (char*)d_ws;
    unsigned short* l12cat = (unsigned short*)(ws);                 // [B][4096][256] bf16, 64 MB
    unsigned short* l3     = (unsigned short*)(ws + 67108864);      // [B][4096][128] bf16, 32 MB
    unsigned short* prevs  = l3;                                     // reused after aux conv
    unsigned short* auxb   = (unsigned short*)(ws + 100663296);     // [B][1024][128] bf16, 8 MB
    unsigned short* bo2b   = (unsigned short*)(ws + 109051904);     // [B][1024][128] bf16, 8 MB
    float* attn   = (float*)(ws + 117440512);                        // 512 KB
    float* logits = (float*)(ws + 117964800);                        // 512 KB
    unsigned short* wT = (unsigned short*)(ws + 118489088);          // 1.92 MB

    // t1/tp scratch live in d_out (48 MB = exactly 16+32); fully consumed by the
    // prev conv before fuse_roi_k overwrites d_out with the real outputs.
    unsigned short* t1 = (unsigned short*)d_out;                     // [B][4096][64] bf16
    unsigned short* tp = t1 + (size_t)B * HW * 64;                   // [B][4096][128] bf16

    float* o0 = (float*)d_out;
    float* o1 = o0 + (size_t)B * 128 * 1024;
    float* o2 = o1 + (size_t)B * 128 * 1024;

    wprep_k<<<dim3(416), dim3(256), 0, stream>>>(w1, w2, w3, w_aux, w_b2, w_prev, wT);
    tr_k<<<dim3(16, B, 2), dim3(256), 0, stream>>>(out1, out2, out3, t1, tp);
    logits_k<<<dim3(B * 16), dim3(256), 0, stream>>>(out1, lin_w, lin_b, logits);
    softmax_k<<<dim3(B), dim3(256), 0, stream>>>(logits, attn);

    // l1 = lrelu(conv(out1,w1)) -> l12cat ch 0..127
    conv_k<64, 1, 64, 0, 256, 0, false><<<dim3(64, B), dim3(256), 0, stream>>>(
        t1, wT + 0, b1, nullptr, l12cat);
    // l2 = lrelu(conv(l1,w2)) -> l12cat ch 128..255
    conv_k<128, 1, 256, 0, 256, 128, false><<<dim3(64, B), dim3(256), 0, stream>>>(
        l12cat, wT + 73728, b2, nullptr, l12cat);
    // l3 = lrelu(conv(l2,w3))
    conv_k<128, 1, 256, 128, 128, 0, false><<<dim3(64, B), dim3(256), 0, stream>>>(
        l12cat, wT + 221184, b3, nullptr, l3);
    // aux = lrelu(conv(l3,w_aux,s2))
    conv_k<128, 2, 128, 0, 128, 0, false><<<dim3(16, B), dim3(256), 0, stream>>>(
        l3, wT + 368640, b_aux, nullptr, auxb);
    // block_out2 = lrelu(conv(concat(l1,l2),w_b2,s2))
    conv_k<256, 2, 256, 0, 128, 0, false><<<dim3(16, B), dim3(256), 0, stream>>>(
        l12cat, wT + 516096, b_b2, nullptr, bo2b);
    // prevs = lrelu(conv(concat(out2,out3),w_prev)) * attn   (overwrites l3 slot)
    conv_k<128, 1, 128, 0, 128, 0, true><<<dim3(64, B), dim3(256), 0, stream>>>(
        tp, wT + 811008, b_prev, attn, prevs);

    fuse_roi_k<<<dim3(2048), dim3(256), 0, stream>>>(prevs, l12cat, auxb, bo2b, o0, o1, o2);
}